// Round 1
// baseline (157.929 us; speedup 1.0000x reference)
//
#include <hip/hip_runtime.h>
#include <stdint.h>

static constexpr int Mrows = 16384;   // B*N = 64*256
static constexpr int Kdim  = 1024;    // L
static constexpr int Ncols = 512;     // OUT

typedef __attribute__((ext_vector_type(8))) short bf16x8;
typedef __attribute__((ext_vector_type(4))) float f32x4;

__device__ __forceinline__ unsigned short f2bf(float f) {
  unsigned u = __builtin_bit_cast(unsigned, f);
  u += 0x7FFFu + ((u >> 16) & 1u);          // RNE
  return (unsigned short)(u >> 16);
}
__device__ __forceinline__ unsigned f2bf2(float lo, float hi) {
  unsigned ul = __builtin_bit_cast(unsigned, lo);
  unsigned uh = __builtin_bit_cast(unsigned, hi);
  ul += 0x7FFFu + ((ul >> 16) & 1u);
  uh += 0x7FFFu + ((uh >> 16) & 1u);
  return (ul >> 16) | (uh & 0xFFFF0000u);
}

// async global->LDS, 16B per lane; LDS dest = uniform base + lane*16
__device__ __forceinline__ void gl2lds16(const void* g, void* l) {
  __builtin_amdgcn_global_load_lds(
      (const __attribute__((address_space(1))) void*)g,
      (__attribute__((address_space(3))) void*)l, 16, 0, 0);
}

// ---------------------------------------------------------------------------
// prep_w: 512 blocks: Wt[n][k] = bf16(0.5*(W_in+W_out)+W_root)^T.  ~7 MiB of
// traffic total -- a few microseconds.  (X conversion is now fused into gemm.)
// ---------------------------------------------------------------------------
__global__ __launch_bounds__(256) void prep_w(
    const float* __restrict__ Win, const float* __restrict__ Wout,
    const float* __restrict__ Wroot, unsigned short* __restrict__ Wt)
{
  __shared__ unsigned short lds[32 * 36];
  const int t  = threadIdx.x;
  const int b2 = blockIdx.x;
  const int tk0 = (b2 & 31) * 32;          // 1024/32 = 32 K-tiles
  const int tn0 = (b2 >> 5) * 32;          // 512/32  = 16 N-tiles
  {
    const int k  = t >> 3;                 // 0..31
    const int nq = (t & 7) * 4;            // 0,4,..,28
    const int gi = (tk0 + k) * Ncols + tn0 + nq;
    const float4 wi = *(const float4*)(Win + gi);
    const float4 wo = *(const float4*)(Wout + gi);
    const float4 wr = *(const float4*)(Wroot + gi);
    lds[(nq + 0) * 36 + k] = f2bf(0.5f * (wi.x + wo.x) + wr.x);
    lds[(nq + 1) * 36 + k] = f2bf(0.5f * (wi.y + wo.y) + wr.y);
    lds[(nq + 2) * 36 + k] = f2bf(0.5f * (wi.z + wo.z) + wr.z);
    lds[(nq + 3) * 36 + k] = f2bf(0.5f * (wi.w + wo.w) + wr.w);
  }
  __syncthreads();
  {
    const int n  = t >> 3;                 // 0..31
    const int k8 = (t & 7) * 4;            // 0,4,..,28
    const ushort4 v = *(const ushort4*)&lds[n * 36 + k8];
    *(ushort4*)(Wt + (size_t)(tn0 + n) * Kdim + tk0 + k8) = v;
  }
}

// ---------------------------------------------------------------------------
// gemm_fused: Y[16384][512] = bf16(x) @ Wt^T + bias.  128x128 tile, BK=32,
// 4 waves 2x2, each wave 64x64 (4x4 mfma_f32_16x16x32_bf16).
//   A side: reg-staged straight from f32 x -- load 2x float4 per row, pack to
//     bf16 in-register, ds_write_b128 into the SAME swizzled layout as before
//     (16B slot s of row r holds k-chunk s^((r>>1)&3)), so fragment reads are
//     unchanged.  A-loads for it+1 are issued under the MFMAs, and barrier #2
//     is lgkmcnt(0)+s_barrier only (no vmcnt drain) so they stay in flight.
//   B side: global_load_lds width=16 from the tiny L2-resident Wt, as before.
// x re-reads across the 4 n-tiles hit L2/L3 (blocks sharing an m-panel are
// bid+{0,128,256,384} -> same XCD under %8 round-robin).
// ---------------------------------------------------------------------------
__global__ __launch_bounds__(256, 2) void gemm_fused(
    const float* __restrict__ x, const unsigned short* __restrict__ Wt,
    const float* __restrict__ b_in, const float* __restrict__ b_out,
    const float* __restrict__ b_root, float* __restrict__ Y)
{
  __shared__ __attribute__((aligned(16))) short As[128 * 32];
  __shared__ __attribute__((aligned(16))) short Bs[128 * 32];

  const int bid = blockIdx.x;
  const int m0 = (bid & 127) * 128;
  const int n0 = (bid >> 7) * 128;

  const int t    = threadIdx.x;
  const int lane = t & 63;
  const int w    = t >> 6;
  const int wm   = w >> 1;
  const int wn   = w & 1;
  const int quad = lane >> 4;
  const int lm   = lane & 15;

  // --- staging addresses: each wave covers 32 rows of A and 32 rows of B
  const int sr = lane >> 2;                  // row within 16-row group
  const int ss = lane & 3;                   // LDS 16B slot within row
  const int sc = ss ^ ((sr >> 1) & 3);       // global chunk fetched into it
  const float* gX          = x  + (size_t)(m0 + w * 32 + sr) * Kdim + sc * 8;
  const unsigned short* gB = Wt + (size_t)(n0 + w * 32 + sr) * Kdim + sc * 8;
  short* const lA0 = &As[(w * 32 + sr) * 32 + ss * 8];   // per-lane ds_write dest
  short* const lA1 = lA0 + 16 * 32;
  short* const lB0 = &Bs[(w * 32) * 32];                 // wave-uniform gl2lds base
  short* const lB1 = &Bs[(w * 32 + 16) * 32];
  const int rowK = 16 * Kdim;                // +16 rows in global

  // --- fragment addresses (unchanged layout)
  const int slot = quad ^ ((lm >> 1) & 3);
  const int aoff = (wm * 64 + lm) * 32 + slot * 8;
  const int boff = (wn * 64 + lm) * 32 + slot * 8;

  f32x4 acc[4][4] = {};

  // prologue: A f32 loads for it=0
  float4 a00 = *(const float4*)(gX);
  float4 a01 = *(const float4*)(gX + 4);
  float4 a10 = *(const float4*)(gX + rowK);
  float4 a11 = *(const float4*)(gX + rowK + 4);

  #pragma unroll 1
  for (int it = 0; it < 32; ++it) {
    // B staging for this tile (LDS safe: prev frags drained at barrier #2)
    gl2lds16(gB + it * 32,        lB0);
    gl2lds16(gB + it * 32 + rowK, lB1);

    // A pack (waits on the prefetched f32 loads) + swizzled ds_write_b128
    uint4 pa, pb;
    pa.x = f2bf2(a00.x, a00.y); pa.y = f2bf2(a00.z, a00.w);
    pa.z = f2bf2(a01.x, a01.y); pa.w = f2bf2(a01.z, a01.w);
    pb.x = f2bf2(a10.x, a10.y); pb.y = f2bf2(a10.z, a10.w);
    pb.z = f2bf2(a11.x, a11.y); pb.w = f2bf2(a11.z, a11.w);
    *(uint4*)lA0 = pa;
    *(uint4*)lA1 = pb;

    __syncthreads();                         // drains B vmcnt + A lgkm: tile visible

    bf16x8 af[4], bfr[4];
    #pragma unroll
    for (int i = 0; i < 4; ++i) af[i]  = *(const bf16x8*)&As[aoff + i * 16 * 32];
    #pragma unroll
    for (int j = 0; j < 4; ++j) bfr[j] = *(const bf16x8*)&Bs[boff + j * 16 * 32];

    // issue next A f32 loads now: latency hides under the 16 MFMAs and stays
    // in flight across the lgkm-only barrier below
    if (it < 31) {
      const float* gx = gX + (it + 1) * 32;
      a00 = *(const float4*)(gx);
      a01 = *(const float4*)(gx + 4);
      a10 = *(const float4*)(gx + rowK);
      a11 = *(const float4*)(gx + rowK + 4);
    }

    #pragma unroll
    for (int i = 0; i < 4; ++i)
      #pragma unroll
      for (int j = 0; j < 4; ++j)
        acc[i][j] = __builtin_amdgcn_mfma_f32_16x16x32_bf16(af[i], bfr[j], acc[i][j], 0, 0, 0);

    // barrier #2: frags consumed before overwrite.  Only LDS reads need
    // draining -- do NOT use __syncthreads() (vmcnt(0) would stall on the
    // just-issued A prefetch).
    asm volatile("s_waitcnt lgkmcnt(0)" ::: "memory");
    __builtin_amdgcn_s_barrier();
  }

  // epilogue: D[row=(lane>>4)*4+reg][col=lane&15] per 16x16 tile; bias fused
  #pragma unroll
  for (int j = 0; j < 4; ++j) {
    const int gc = n0 + wn * 64 + j * 16 + lm;
    const float bias = 0.5f * (b_in[gc] + b_out[gc]) + b_root[gc];
    #pragma unroll
    for (int i = 0; i < 4; ++i) {
      const int gr = m0 + wm * 64 + i * 16 + quad * 4;
      float* yp = Y + (size_t)gr * Ncols + gc;
      #pragma unroll
      for (int r = 0; r < 4; ++r)
        yp[(size_t)r * Ncols] = acc[i][j][r] + bias;
    }
  }
}

// ---------------------------------------------------------------------------
extern "C" void kernel_launch(void* const* d_in, const int* in_sizes, int n_in,
                              void* d_out, int out_size, void* d_ws, size_t ws_size,
                              hipStream_t stream)
{
  const float* x      = (const float*)d_in[0];
  // d_in[1] = At : dead input (ChebConv K=1 -> no neighbor aggregation)
  const float* W_in   = (const float*)d_in[2];
  const float* b_in   = (const float*)d_in[3];
  const float* W_out  = (const float*)d_in[4];
  const float* b_out  = (const float*)d_in[5];
  const float* W_root = (const float*)d_in[6];
  const float* b_root = (const float*)d_in[7];
  float* y = (float*)d_out;

  unsigned short* Wt = (unsigned short*)d_ws;   // 1 MiB only

  prep_w<<<dim3(512), dim3(256), 0, stream>>>(W_in, W_out, W_root, Wt);
  gemm_fused<<<dim3(512), dim3(256), 0, stream>>>(x, Wt, b_in, b_out, b_root, y);
}